// Round 2
// baseline (21.843 us; speedup 1.0000x reference)
//
#include <hip/hip_runtime.h>
#include <hip/hip_bf16.h>

#define CC 16     // hidden states
#define MM 32     // label alphabet
#define NGEN 16   // generators

// One block of 512 threads: thread = m*16 + g computes
// T[m][g] = sum_c posterior[c]*log(numerator[c]) with softmax(B) over M and
// softmax(Pi) over C. All fp32.
__global__ void cgmm_table_kernel(const float* __restrict__ B,
                                  const float* __restrict__ Pi,
                                  float* __restrict__ T) {
    __shared__ float denomB[CC][NGEN];   // sum_m exp(B[c][m][g])
    __shared__ float smPi[CC][NGEN];     // softmax(Pi) over c
    __shared__ float denomPi[NGEN];

    const int tid = threadIdx.x;  // 0..511

    if (tid < CC * NGEN) {
        const int c = tid >> 4, g = tid & 15;
        float s = 0.f;
        #pragma unroll
        for (int m = 0; m < MM; ++m)
            s += expf(B[(c * MM + m) * NGEN + g]);
        denomB[c][g] = s;
    }
    if (tid >= 256 && tid < 256 + NGEN) {
        const int g = tid - 256;
        float s = 0.f;
        #pragma unroll
        for (int c = 0; c < CC; ++c)
            s += expf(Pi[c * NGEN + g]);
        denomPi[g] = s;
    }
    __syncthreads();
    if (tid < CC * NGEN) {
        const int c = tid >> 4, g = tid & 15;
        smPi[c][g] = expf(Pi[c * NGEN + g]) / denomPi[g];
    }
    __syncthreads();

    const int m = tid >> 4;   // 0..31
    const int g = tid & 15;   // 0..15

    float num[CC];
    float s = 0.f;
    #pragma unroll
    for (int c = 0; c < CC; ++c) {
        const float pb = expf(B[(c * MM + m) * NGEN + g]) / denomB[c][g];
        num[c] = smPi[c][g] * pb;
        s += num[c];
    }
    float lik = 0.f;
    const float inv_s = 1.0f / s;
    #pragma unroll
    for (int c = 0; c < CC; ++c)
        lik += (num[c] * inv_s) * logf(num[c]);

    T[m * NGEN + g] = lik;
}

// One 64-thread block per graph. batch is sorted, so the graph's nodes are a
// contiguous range found by two binary searches. lane -> (gen = tid&15,
// chunk = tid>>4); fp32 accumulate T[x[n]][gen]; shuffle-reduce over the 4
// chunks; lanes 0..15 write the 16 outputs. Deterministic, no atomics.
__global__ void __launch_bounds__(64) cgmm_graph_kernel(
        const int* __restrict__ x,
        const int* __restrict__ batch,
        const float* __restrict__ T,
        float* __restrict__ out,
        int n_nodes) {
    __shared__ float Tl[MM * NGEN];
    const int tid = threadIdx.x;
    for (int i = tid; i < MM * NGEN; i += 64) Tl[i] = T[i];

    const int gid = blockIdx.x;

    // start = lower_bound(batch, gid)
    int lo = 0, hi = n_nodes;
    while (lo < hi) {
        const int mid = (lo + hi) >> 1;
        if (batch[mid] < gid) lo = mid + 1; else hi = mid;
    }
    const int start = lo;
    // end = lower_bound(batch, gid + 1), searched in [start, n_nodes)
    hi = n_nodes;
    while (lo < hi) {
        const int mid = (lo + hi) >> 1;
        if (batch[mid] < gid + 1) lo = mid + 1; else hi = mid;
    }
    const int end = lo;

    __syncthreads();

    const int g = tid & 15;
    const int chunk = tid >> 4;   // 0..3

    float acc = 0.f;
    for (int n = start + chunk; n < end; n += 4)
        acc += Tl[x[n] * NGEN + g];

    // reduce lanes {g, g+16, g+32, g+48}
    acc += __shfl_down(acc, 32);
    acc += __shfl_down(acc, 16);

    if (tid < NGEN)
        out[gid * NGEN + tid] = -acc;
}

extern "C" void kernel_launch(void* const* d_in, const int* in_sizes, int n_in,
                              void* d_out, int out_size, void* d_ws, size_t ws_size,
                              hipStream_t stream) {
    const int* x     = (const int*)d_in[0];
    // d_in[1] = edge_index : unused by layer 0 (never read)
    const int* batch = (const int*)d_in[2];
    const float* B   = (const float*)d_in[3];
    const float* Pi  = (const float*)d_in[4];
    float* out       = (float*)d_out;
    float* T         = (float*)d_ws;   // 32*16 floats = 2 KiB scratch

    const int n_nodes  = in_sizes[0];
    const int n_graphs = out_size / NGEN;

    hipLaunchKernelGGL(cgmm_table_kernel, dim3(1), dim3(512), 0, stream, B, Pi, T);
    hipLaunchKernelGGL(cgmm_graph_kernel, dim3(n_graphs), dim3(64), 0, stream,
                       x, batch, T, out, n_nodes);
}

// Round 3
// 18.778 us; speedup vs baseline: 1.1632x; 1.1632x over previous
//
#include <hip/hip_runtime.h>
#include <hip/hip_bf16.h>

#define CC 16     // hidden states
#define MM 32     // label alphabet
#define NGEN 16   // generators

// One block, 512 threads: thread = m*16+g computes
// T[m][g] = sum_c posterior[c]*log(numerator[c]), softmax(B) over M,
// softmax(Pi) over C. exp(B) computed ONCE (regs + LDS for the denom sums).
__global__ void __launch_bounds__(512) cgmm_table_kernel(
        const float* __restrict__ B,
        const float* __restrict__ Pi,
        float* __restrict__ T) {
    __shared__ float E[CC][MM][NGEN];     // exp(B), 32 KB
    __shared__ float denomB[CC][NGEN];    // sum_m exp(B[c][m][g])
    __shared__ float smPi[CC][NGEN];      // exp(Pi) -> softmax(Pi)
    __shared__ float denomPi[NGEN];

    const int tid = threadIdx.x;          // 0..511
    const int m = tid >> 4;               // 0..31
    const int g = tid & 15;               // 0..15

    float e[CC];
    #pragma unroll
    for (int c = 0; c < CC; ++c) {
        e[c] = expf(B[(c * MM + m) * NGEN + g]);
        E[c][m][g] = e[c];
    }
    if (tid < CC * NGEN)
        smPi[tid >> 4][tid & 15] = expf(Pi[tid]);   // exp(Pi), normalized later
    __syncthreads();

    if (tid < CC * NGEN) {
        const int c2 = tid >> 4, g2 = tid & 15;
        float s = 0.f;
        #pragma unroll
        for (int mm = 0; mm < MM; ++mm) s += E[c2][mm][g2];
        denomB[c2][g2] = s;
    }
    if (tid < NGEN) {
        float s = 0.f;
        #pragma unroll
        for (int c2 = 0; c2 < CC; ++c2) s += smPi[c2][tid];
        denomPi[tid] = s;
    }
    __syncthreads();
    if (tid < CC * NGEN)
        smPi[tid >> 4][tid & 15] /= denomPi[tid & 15];
    __syncthreads();

    float num[CC];
    float s = 0.f;
    #pragma unroll
    for (int c = 0; c < CC; ++c) {
        num[c] = smPi[c][g] * (e[c] / denomB[c][g]);
        s += num[c];
    }
    float lik = 0.f;
    const float inv_s = 1.0f / s;
    #pragma unroll
    for (int c = 0; c < CC; ++c)
        lik += (num[c] * inv_s) * logf(num[c]);

    T[m * NGEN + g] = lik;
}

// One 64-thread block per graph. Wave-parallel 32-ary lower_bound:
// lanes 0-31 search target=gid, lanes 32-63 target=gid+1 (both bounds found
// concurrently, ~4 dependent load levels instead of 2x19). Then lane ->
// (gen = tid&15, chunk = tid>>4) accumulates T[x[n]][gen] in fp32,
// shuffle-reduce over chunks, lanes 0..15 write. Deterministic, no atomics.
__global__ void __launch_bounds__(64) cgmm_graph_kernel(
        const int* __restrict__ x,
        const int* __restrict__ batch,
        const float* __restrict__ T,
        float* __restrict__ out,
        int n_nodes) {
    __shared__ float Tl[MM * NGEN];
    const int tid = threadIdx.x;
    for (int i = tid; i < MM * NGEN; i += 64) Tl[i] = T[i];

    const int gid = blockIdx.x;
    const int half = tid >> 5;            // 0: start-search, 1: end-search
    const int li   = tid & 31;            // lane within half
    const int target = gid + half;        // lower_bound target

    int lo = 0, hi = n_nodes;             // boundary in [lo, hi]
    while (hi - lo > 32) {
        const int step = (hi - lo) >> 5;  // >= 1
        const int p = lo + li * step;     // 32 probes, p0 = lo
        const bool c = batch[p] < target;
        const unsigned mask = (unsigned)(__ballot(c) >> (half << 5));
        const int k = __popc(mask);       // monotone: first k probes true
        if (k == 0) {
            hi = lo;                      // boundary == lo
        } else {
            const int nhi = (k < 32) ? (lo + k * step) : hi;
            lo = lo + (k - 1) * step + 1;
            hi = nhi;
        }
    }
    int bound;
    {
        const int p = lo + li;
        const bool c = (p < hi) && (batch[p] < target);
        const unsigned mask = (unsigned)(__ballot(c) >> (half << 5));
        bound = lo + __popc(mask);
    }
    const int start = __shfl(bound, 0);
    const int end   = __shfl(bound, 32);

    __syncthreads();

    const int g = tid & 15;
    const int chunk = tid >> 4;           // 0..3

    float acc = 0.f;
    for (int n = start + chunk; n < end; n += 4)
        acc += Tl[x[n] * NGEN + g];

    // reduce lanes {g, g+16, g+32, g+48}
    acc += __shfl_down(acc, 32);
    acc += __shfl_down(acc, 16);

    if (tid < NGEN)
        out[gid * NGEN + tid] = -acc;
}

extern "C" void kernel_launch(void* const* d_in, const int* in_sizes, int n_in,
                              void* d_out, int out_size, void* d_ws, size_t ws_size,
                              hipStream_t stream) {
    const int* x     = (const int*)d_in[0];
    // d_in[1] = edge_index : unused by layer 0 (never read)
    const int* batch = (const int*)d_in[2];
    const float* B   = (const float*)d_in[3];
    const float* Pi  = (const float*)d_in[4];
    float* out       = (float*)d_out;
    float* T         = (float*)d_ws;   // 32*16 floats = 2 KiB scratch

    const int n_nodes  = in_sizes[0];
    const int n_graphs = out_size / NGEN;

    hipLaunchKernelGGL(cgmm_table_kernel, dim3(1), dim3(512), 0, stream, B, Pi, T);
    hipLaunchKernelGGL(cgmm_graph_kernel, dim3(n_graphs), dim3(64), 0, stream,
                       x, batch, T, out, n_nodes);
}

// Round 4
// 13.963 us; speedup vs baseline: 1.5644x; 1.3449x over previous
//
#include <hip/hip_runtime.h>
#include <hip/hip_bf16.h>

#define CC 16     // hidden states
#define MM 32     // label alphabet
#define NGEN 16   // generators
#define TLP 17    // padded LDS stride for T table

// Grid of 256-thread blocks. Block 0 computes the 32x16 table T:
//   T[m][g] = sum_c (num[c]/s) * log(num[c]),  num[c] = smPi[c][g]*smB[c][m][g]
// using log(num[c]) = Pi[c][g] + B[c][m][g] - log(dPi[g]) - log(dB[c][g])
// so only 272 logf total (vs 8192 naively). Blocks 1.. scan the sorted batch
// array and write offs[gph] = lower_bound(batch, gph) for gph in [0, n_graphs].
__global__ void __launch_bounds__(256) cgmm_prep_kernel(
        const float* __restrict__ B,
        const float* __restrict__ Pi,
        const int* __restrict__ batch,
        float* __restrict__ T,
        int* __restrict__ offs,
        int n_nodes, int n_graphs) {
    if (blockIdx.x == 0) {
        __shared__ float E[CC][MM][NGEN];   // exp(B), 32 KB
        __shared__ float Acg[CC][NGEN];     // ePi/(dPi*dB)
        __shared__ float Lcg[CC][NGEN];     // Pi - log dPi - log dB
        __shared__ float ePi[CC][NGEN];
        __shared__ float dPi[NGEN];

        const int tid = threadIdx.x;        // 0..255
        const int c = tid >> 4, g = tid & 15;

        float s = 0.f;
        #pragma unroll
        for (int m = 0; m < MM; ++m) {
            const float e = expf(B[(c * MM + m) * NGEN + g]);
            E[c][m][g] = e;
            s += e;
        }
        const float dB = s;
        ePi[c][g] = expf(Pi[c * NGEN + g]);
        __syncthreads();
        if (tid < NGEN) {
            float t = 0.f;
            #pragma unroll
            for (int cc = 0; cc < CC; ++cc) t += ePi[cc][tid];
            dPi[tid] = t;
        }
        __syncthreads();
        Acg[c][g] = ePi[c][g] / (dPi[g] * dB);
        Lcg[c][g] = Pi[c * NGEN + g] - logf(dPi[g]) - logf(dB);
        __syncthreads();

        // 512 (m,g) cells over 256 threads
        #pragma unroll
        for (int r = 0; r < 2; ++r) {
            const int m = (tid >> 4) + r * 16;
            float ssum = 0.f, lsum = 0.f;
            #pragma unroll
            for (int cc = 0; cc < CC; ++cc) {
                const float ne = Acg[cc][g] * E[cc][m][g];
                ssum += ne;
                lsum += ne * (Lcg[cc][g] + B[(cc * MM + m) * NGEN + g]);
            }
            T[m * NGEN + g] = lsum / ssum;
        }
    } else {
        // boundary scan: batch sorted; offs[gph] = first n with batch[n] >= gph
        const int idx = (blockIdx.x - 1) * blockDim.x + threadIdx.x;
        const int stride = (gridDim.x - 1) * blockDim.x;
        for (int n = idx; n < n_nodes; n += stride) {
            const int b = batch[n];
            const int prev = (n == 0) ? -1 : batch[n - 1];
            for (int gph = prev + 1; gph <= b; ++gph) offs[gph] = n;
            if (n == n_nodes - 1)
                for (int gph = b + 1; gph <= n_graphs; ++gph) offs[gph] = n_nodes;
        }
    }
}

// 4 graphs per 256-thread block (one per wave). Tl staged once per block
// (padded stride 17 to spread LDS banks). Per wave: lane -> (gen = lane&15,
// chunk = lane>>4); fp32 accumulate T[x[n]][gen] over chunk-strided nodes,
// 4x unrolled for load ILP; shuffle-reduce; lanes 0..15 write.
__global__ void __launch_bounds__(256) cgmm_graph_kernel(
        const int* __restrict__ x,
        const int* __restrict__ offs,
        const float* __restrict__ T,
        float* __restrict__ out,
        int n_graphs) {
    __shared__ float Tl[MM * TLP];
    const int tid = threadIdx.x;
    for (int i = tid; i < MM * NGEN; i += 256)
        Tl[(i >> 4) * TLP + (i & 15)] = T[i];

    const int lane = tid & 63;
    const int gid = blockIdx.x * 4 + (tid >> 6);
    __syncthreads();

    if (gid < n_graphs) {
        const int start = offs[gid];
        const int end   = offs[gid + 1];
        const int g = lane & 15;
        const int chunk = lane >> 4;     // 0..3

        float acc = 0.f;
        int n = start + chunk;
        for (; n + 12 < end; n += 16) {
            const int x0 = x[n], x1 = x[n + 4], x2 = x[n + 8], x3 = x[n + 12];
            acc += Tl[x0 * TLP + g];
            acc += Tl[x1 * TLP + g];
            acc += Tl[x2 * TLP + g];
            acc += Tl[x3 * TLP + g];
        }
        for (; n < end; n += 4) acc += Tl[x[n] * TLP + g];

        // reduce lanes {g, g+16, g+32, g+48} within the wave
        acc += __shfl_down(acc, 32);
        acc += __shfl_down(acc, 16);

        if (lane < NGEN) out[gid * NGEN + lane] = -acc;
    }
}

extern "C" void kernel_launch(void* const* d_in, const int* in_sizes, int n_in,
                              void* d_out, int out_size, void* d_ws, size_t ws_size,
                              hipStream_t stream) {
    const int* x     = (const int*)d_in[0];
    // d_in[1] = edge_index : unused by layer 0 (never read)
    const int* batch = (const int*)d_in[2];
    const float* B   = (const float*)d_in[3];
    const float* Pi  = (const float*)d_in[4];
    float* out       = (float*)d_out;
    float* T         = (float*)d_ws;                 // 512 floats
    int*   offs      = (int*)((char*)d_ws + 4096);   // n_graphs+1 ints

    const int n_nodes  = in_sizes[0];
    const int n_graphs = out_size / NGEN;

    hipLaunchKernelGGL(cgmm_prep_kernel, dim3(256), dim3(256), 0, stream,
                       B, Pi, batch, T, offs, n_nodes, n_graphs);
    hipLaunchKernelGGL(cgmm_graph_kernel, dim3((n_graphs + 3) / 4), dim3(256), 0, stream,
                       x, offs, T, out, n_graphs);
}